// Round 6
// baseline (981.977 us; speedup 1.0000x reference)
//
#include <hip/hip_runtime.h>
#include <stdint.h>

// Problem constants (from the reference; ALL TENSORS FP32)
#define NPOS 2394          // 38*63
#define CIN 512
#define KK 4608            // 512*9
#define NANCH 21546        // NPOS*9
#define PRE 6000
#define POST 300
#define NWORD 94           // ceil(6000/64)
#define NQ 8
#define QLEN 2694          // ceil(21546/8)

// ---- d_out scratch map (bytes). out bytes = 300*512*49*4 = 30,105,600.
// All transients live in d_out; final k_crop overwrites the whole buffer.
#define OFF_BTT   0              // Btt 9,437,184 (s2->s3); mask 4,512,000 (s8->s9) aliased
#define OFF_RPNT  9437184        // rpnT 4,902,912 (s3->s4)
#define OFF_SBOX  9437184        // sboxes 96,000 (s6->s10) aliases dead rpnT
#define OFF_KEEP  9533440        // keep 1,200 (s9->s10)
#define OFF_KEYS  14340096       // keys 172,368 (s4->s5)
#define OFF_PROP  14512640       // proposals 344,736 (s4->s7)
#define OFF_RPART 14857472       // rpart 689,472 (s5->s7)
#define OFF_FEATT 15547136       // featT 4,902,912 (s1->s3); ends 20,450,048 < 30,105,600

// fp32 (2394,512) channel-last transpose of net (512,2394), via LDS 32x32 tiles
__global__ __launch_bounds__(256) void k_transpose_feat(const float* __restrict__ in,
                                                        float* __restrict__ featT) {
    __shared__ float tl[32][33];
    int tx = threadIdx.x & 31, tg = threadIdx.x >> 5;     // 32 x 8
    int posBase = blockIdx.x * 32, ciBase = blockIdx.y * 32;
#pragma unroll
    for (int j = 0; j < 4; ++j) {
        int ci = ciBase + tg + j * 8;
        int pos = posBase + tx;
        tl[tg + j * 8][tx] = (pos < NPOS) ? in[(size_t)ci * NPOS + pos] : 0.f;
    }
    __syncthreads();
#pragma unroll
    for (int j = 0; j < 4; ++j) {
        int pos = posBase + tg + j * 8;
        int ci = ciBase + tx;
        if (pos < NPOS) featT[(size_t)pos * 512 + ci] = tl[tx][tg + j * 8];
    }
}

// w_rpn (co,ci,3,3) -> Btt[co][p*512+ci]
__global__ void k_prep_w(const float* __restrict__ w, float* __restrict__ Btt) {
    int idx = blockIdx.x * 256 + threadIdx.x;
    if (idx >= CIN * KK) return;
    int co = idx / KK;
    int rem = idx - co * KK;
    int p = rem >> 9;
    int ci = rem & 511;
    Btt[idx] = w[(co * CIN + ci) * 9 + p];
}

// 3x3 SAME conv as implicit-im2col fp32 SGEMM: C[pos][co] = sum_k A[pos][k]*B[co][k].
// 64x64 tile, 256 threads (16x16), 4x4 outputs/thread, K staged 16-wide in LDS.
__global__ __launch_bounds__(256) void k_conv3(const float* __restrict__ featT,
                                               const float* __restrict__ Btt,
                                               const float* __restrict__ brpn,
                                               float* __restrict__ rpnT) {
    __shared__ float As[16][68];   // [k][pos]  (68: keep float4 alignment, spread banks)
    __shared__ float Bs[16][68];   // [k][co]
    int t = threadIdx.x;
    int posBase = blockIdx.x * 64, coBase = blockIdx.y * 64;
    int tx = t & 15, ty = t >> 4;
    float acc[4][4] = {{0.f}};
    int r = t >> 2, q = t & 3;          // staging: row r (0..63), quad q
    int pos = posBase + r;
    int h = pos / 63, w = pos - h * 63;

    for (int kc = 0; kc < 288; ++kc) {   // 4608 / 16
        int p = kc >> 5;                 // kh*3+kw  (16 | 512 so no straddle)
        int ci0 = (kc & 31) << 4;
        int kh = p / 3, kw = p - kh * 3;
        int hy = h + kh - 1, wx = w + kw - 1;
        float4 av = make_float4(0.f, 0.f, 0.f, 0.f);
        if ((unsigned)hy < 38u && (unsigned)wx < 63u && pos < NPOS)
            av = *reinterpret_cast<const float4*>(featT + ((hy * 63 + wx) * 512 + ci0 + q * 4));
        float4 bv = *reinterpret_cast<const float4*>(Btt + (size_t)(coBase + r) * KK + kc * 16 + q * 4);
        __syncthreads();
        As[q * 4 + 0][r] = av.x; As[q * 4 + 1][r] = av.y;
        As[q * 4 + 2][r] = av.z; As[q * 4 + 3][r] = av.w;
        Bs[q * 4 + 0][r] = bv.x; Bs[q * 4 + 1][r] = bv.y;
        Bs[q * 4 + 2][r] = bv.z; Bs[q * 4 + 3][r] = bv.w;
        __syncthreads();
#pragma unroll
        for (int k = 0; k < 16; ++k) {
            float4 a4 = *reinterpret_cast<const float4*>(&As[k][ty * 4]);
            float4 b4 = *reinterpret_cast<const float4*>(&Bs[k][tx * 4]);
            float a[4] = {a4.x, a4.y, a4.z, a4.w};
            float b[4] = {b4.x, b4.y, b4.z, b4.w};
#pragma unroll
            for (int i = 0; i < 4; ++i)
#pragma unroll
                for (int j = 0; j < 4; ++j) acc[i][j] += a[i] * b[j];
        }
    }
#pragma unroll
    for (int i = 0; i < 4; ++i) {
        int opos = posBase + ty * 4 + i;
        if (opos >= NPOS) continue;
#pragma unroll
        for (int j = 0; j < 4; ++j) {
            int co = coBase + tx * 4 + j;
            float v = acc[i][j] + brpn[co];
            rpnT[(size_t)opos * 512 + co] = v > 0.f ? v : 0.f;   // ReLU
        }
    }
}

// 1x1 heads + softmax-prob + box decode + clip + sort key. One block per position.
__global__ __launch_bounds__(256) void k_heads(const float* __restrict__ rpnT,
                                               const float* __restrict__ wcls,
                                               const float* __restrict__ bcls,
                                               const float* __restrict__ wbbox,
                                               const float* __restrict__ bbbox,
                                               const float* __restrict__ anchors,
                                               float* __restrict__ proposals,
                                               unsigned long long* __restrict__ keys) {
    __shared__ float x[512];
    __shared__ float part[54][4];
    __shared__ float logit[54];
    int pos = blockIdx.x;
    int t = threadIdx.x;
    x[t] = rpnT[(size_t)pos * 512 + t];
    x[t + 256] = rpnT[(size_t)pos * 512 + t + 256];
    __syncthreads();
    if (t < 216) {
        int o = t >> 2, q = t & 3;
        const float* wr = (o < 18) ? (wcls + o * 512) : (wbbox + (o - 18) * 512);
        float s = 0.f;
        int base = q * 128;
#pragma unroll 4
        for (int k2 = 0; k2 < 128; ++k2) s += x[base + k2] * wr[base + k2];
        part[o][q] = s;
    }
    __syncthreads();
    if (t < 54) {
        float b = (t < 18) ? bcls[t] : bbbox[t - 18];
        logit[t] = part[t][0] + part[t][1] + part[t][2] + part[t][3] + b;
    }
    __syncthreads();
    if (t < 9) {
        int a = t;
        float bg = logit[a], fg = logit[9 + a];
        float score = 1.f / (1.f + expf(bg - fg));   // softmax([bg,fg])[1]
        float dx = logit[18 + 4 * a], dy = logit[19 + 4 * a];
        float dw = logit[20 + 4 * a], dh = logit[21 + 4 * a];
        int idx = pos * 9 + a;
        float ax1 = anchors[idx * 4 + 0], ay1 = anchors[idx * 4 + 1];
        float ax2 = anchors[idx * 4 + 2], ay2 = anchors[idx * 4 + 3];
        float aw = ax2 - ax1 + 1.f, ah = ay2 - ay1 + 1.f;
        float cx = ax1 + 0.5f * aw, cy = ay1 + 0.5f * ah;
        float pcx = dx * aw + cx, pcy = dy * ah + cy;
        float pw = expf(dw) * aw, ph = expf(dh) * ah;
        float x1 = fminf(fmaxf(pcx - 0.5f * pw, 0.f), 999.f);
        float y1 = fminf(fmaxf(pcy - 0.5f * ph, 0.f), 599.f);
        float x2 = fminf(fmaxf(pcx + 0.5f * pw, 0.f), 999.f);
        float y2 = fminf(fmaxf(pcy + 0.5f * ph, 0.f), 599.f);
        proposals[idx * 4 + 0] = x1; proposals[idx * 4 + 1] = y1;
        proposals[idx * 4 + 2] = x2; proposals[idx * 4 + 3] = y2;
        union { float f; unsigned int i; } sv; sv.f = score;   // score>0 -> bits monotone
        keys[idx] = (((unsigned long long)sv.i) << 32) |
                    (unsigned long long)(0xFFFFFFFFu - (unsigned)idx);  // ties: lower idx wins
    }
}

// rank_i = #{j : key_j > key_i}; partial counts over 8 j-slices
__global__ __launch_bounds__(256) void k_rank_partial(const unsigned long long* __restrict__ keys,
                                                      unsigned int* __restrict__ rpart) {
    __shared__ unsigned long long kc[1024];
    int i = blockIdx.x * 256 + threadIdx.x;
    int q = blockIdx.y;
    unsigned long long myk = (i < NANCH) ? keys[i] : 0xFFFFFFFFFFFFFFFFull;
    int j0 = q * QLEN;
    int j1 = j0 + QLEN; if (j1 > NANCH) j1 = NANCH;
    unsigned int cnt = 0;
    for (int base = j0; base < j1; base += 1024) {
        int nload = j1 - base; if (nload > 1024) nload = 1024;
        __syncthreads();
        for (int u = threadIdx.x; u < 1024; u += 256)
            kc[u] = (base + u < j1) ? keys[base + u] : 0ull;
        __syncthreads();
        for (int u = 0; u < nload; ++u)
            cnt += (kc[u] > myk) ? 1u : 0u;
    }
    if (i < NANCH) rpart[i * NQ + q] = cnt;
}

__global__ void k_zero_sboxes(float* __restrict__ sboxes) {
    int i = blockIdx.x * 256 + threadIdx.x;
    if (i < PRE * 4) sboxes[i] = 0.f;
}

// scatter into sorted order (keys distinct -> ranks are a permutation)
__global__ void k_rank_scatter(const unsigned int* __restrict__ rpart,
                               const float* __restrict__ proposals,
                               float* __restrict__ sboxes) {
    int i = blockIdx.x * 256 + threadIdx.x;
    if (i >= NANCH) return;
    unsigned int r = 0;
#pragma unroll
    for (int q = 0; q < NQ; q++) r += rpart[i * NQ + q];
    if (r < PRE) {
        sboxes[r * 4 + 0] = proposals[i * 4 + 0];
        sboxes[r * 4 + 1] = proposals[i * 4 + 1];
        sboxes[r * 4 + 2] = proposals[i * 4 + 2];
        sboxes[r * 4 + 3] = proposals[i * 4 + 3];
    }
}

// suppression bitmask: mask[i][jb] bit u set iff iou(i, jb*64+u) > 0.7 and j > i
__global__ __launch_bounds__(64) void k_nms_mask(const float* __restrict__ sboxes,
                                                 unsigned long long* __restrict__ mask) {
    __shared__ float bx[64][4];
    int ib = blockIdx.x, jb = blockIdx.y;
    int lane = threadIdx.x;
    int j = jb * 64 + lane;
    if (j < PRE) {
        bx[lane][0] = sboxes[j * 4 + 0]; bx[lane][1] = sboxes[j * 4 + 1];
        bx[lane][2] = sboxes[j * 4 + 2]; bx[lane][3] = sboxes[j * 4 + 3];
    } else {
        bx[lane][0] = 3e8f; bx[lane][1] = 3e8f; bx[lane][2] = 3e8f; bx[lane][3] = 3e8f;
    }
    __syncthreads();
    int i = ib * 64 + lane;
    if (i >= PRE) return;
    float x1 = sboxes[i * 4 + 0], y1 = sboxes[i * 4 + 1];
    float x2 = sboxes[i * 4 + 2], y2 = sboxes[i * 4 + 3];
    float ar = (x2 - x1 + 1.f) * (y2 - y1 + 1.f);
    unsigned long long bits = 0;
#pragma unroll 4
    for (int u = 0; u < 64; u++) {
        int j2 = jb * 64 + u;
        float iw = fminf(x2, bx[u][2]) - fmaxf(x1, bx[u][0]) + 1.f;
        float ih = fminf(y2, bx[u][3]) - fmaxf(y1, bx[u][1]) + 1.f;
        iw = fmaxf(iw, 0.f); ih = fmaxf(ih, 0.f);
        float inter = iw * ih;
        float arj = (bx[u][2] - bx[u][0] + 1.f) * (bx[u][3] - bx[u][1] + 1.f);
        float iou = inter / (ar + arj - inter);
        if (iou > 0.7f && j2 > i) bits |= (1ull << u);
    }
    mask[(size_t)i * NWORD + jb] = bits;
}

// sequential greedy scan, single wave; removed mask in registers
__global__ __launch_bounds__(64) void k_nms_scan(const unsigned long long* __restrict__ mask,
                                                 int* __restrict__ keep) {
    int lane = threadIdx.x;
    unsigned long long rem0 = 0, rem1 = 0;
    int nk = 0;
    for (int i = 0; i < PRE; ++i) {
        int i6 = i >> 6;
        unsigned long long w = (i6 < 64) ? __shfl(rem0, i6) : __shfl(rem1, i6 - 64);
        if (!((w >> (i & 63)) & 1ull)) {
            if (lane == 0) keep[nk] = i;
            ++nk;
            if (nk == POST) break;
            const unsigned long long* row = mask + (size_t)i * NWORD;
            rem0 |= row[lane];
            if (lane < NWORD - 64) rem1 |= row[64 + lane];
        }
    }
    for (int k2 = nk + lane; k2 < POST; k2 += 64) keep[k2] = PRE - 1;
}

// Single block: reads keep+sboxes into regs (pre-barrier), writes each roi's box
// as a 16-B header at the start of each of its 8 output chunks.
// fp32 chunk (r,cg): bytes [(r*512+cg*64)*196, +12544); headers 16B-aligned.
__global__ __launch_bounds__(256) void k_gather_rois(const float* sboxes, const int* keep,
                                                     float* outF) {
    int t = threadIdx.x;
    float4 box[2];
    int nr = 0;
    for (int r = t; r < POST; r += 256) {
        int ki = keep[r];
        if (ki < 0) ki = 0; if (ki > PRE - 1) ki = PRE - 1;
        box[nr++] = *reinterpret_cast<const float4*>(sboxes + ki * 4);
    }
    __syncthreads();
    nr = 0;
    for (int r = t; r < POST; r += 256) {
        float4 b = box[nr++];
#pragma unroll
        for (int cg = 0; cg < 8; ++cg)
            *reinterpret_cast<float4*>(outF + (size_t)(r * 512 + cg * 64) * 49) = b;
    }
}

// crop_and_resize(14) + 2x2 maxpool. One wave per (roi, 64-ch group); corners
// read from pristine NCHW fp32 net input; box from own chunk header.
__global__ __launch_bounds__(64) void k_crop(const float* __restrict__ net,
                                             float* out) {
    int r = blockIdx.x, cg = blockIdx.y;
    int lane = threadIdx.x;
    int c = cg * 64 + lane;
    const float4 b = *reinterpret_cast<const float4*>(out + (size_t)(r * 512 + cg * 64) * 49);
    float x1 = b.x, y1 = b.y, x2 = b.z, y2 = b.w;
    float by1 = (y1 / 16.f) / 37.f, bx1 = (x1 / 16.f) / 62.f;
    float by2 = (y2 / 16.f) / 37.f, bx2 = (x2 / 16.f) / 62.f;
    float dyn = by2 - by1, dxn = bx2 - bx1;
    const float* fc = net + (size_t)c * NPOS;   // channel-c plane (38x63)
    float* orow = out + ((size_t)r * 512 + c) * 49;
#pragma unroll
    for (int oy = 0; oy < 7; ++oy) {
#pragma unroll
        for (int ox = 0; ox < 7; ++ox) {
            float vv[4];
#pragma unroll
            for (int dy = 0; dy < 2; ++dy) {
                int sy = 2 * oy + dy;
                float ty = (float)sy / 13.f;
                float ys = by1 * 37.f + (ty * dyn) * 37.f;
                float yf = floorf(ys);
                float wy = ys - yf;
                int y0  = (int)fminf(fmaxf(yf, 0.f), 37.f);
                int y1i = (int)fminf(fmaxf(yf + 1.f, 0.f), 37.f);
#pragma unroll
                for (int dxx = 0; dxx < 2; ++dxx) {
                    int sx = 2 * ox + dxx;
                    float tx = (float)sx / 13.f;
                    float xs = bx1 * 62.f + (tx * dxn) * 62.f;
                    float xf = floorf(xs);
                    float wx = xs - xf;
                    int x0  = (int)fminf(fmaxf(xf, 0.f), 62.f);
                    int x1i = (int)fminf(fmaxf(xf + 1.f, 0.f), 62.f);
                    float f00 = fc[y0 * 63 + x0];
                    float f01 = fc[y0 * 63 + x1i];
                    float f10 = fc[y1i * 63 + x0];
                    float f11 = fc[y1i * 63 + x1i];
                    vv[dy * 2 + dxx] = f00 * (1.f - wy) * (1.f - wx) + f01 * (1.f - wy) * wx +
                                       f10 * wy * (1.f - wx) + f11 * wy * wx;
                }
            }
            orow[oy * 7 + ox] = fmaxf(fmaxf(vv[0], vv[1]), fmaxf(vv[2], vv[3]));
        }
    }
}

extern "C" void kernel_launch(void* const* d_in, const int* in_sizes, int n_in,
                              void* d_out, int out_size, void* d_ws, size_t ws_size,
                              hipStream_t stream) {
    (void)d_ws; (void)ws_size;
    // Order-proof binding (all 8 inputs have distinct element counts)
    auto find = [&](int count, int fallback) {
        for (int i = 0; i < n_in; ++i) if (in_sizes[i] == count) return i;
        return fallback;
    };
    const float* net   = (const float*)d_in[find(NPOS * CIN, 0)];
    const float* wrpn  = (const float*)d_in[find(512 * KK, 1)];
    const float* brpn  = (const float*)d_in[find(512, 2)];
    const float* wcls  = (const float*)d_in[find(18 * 512, 3)];
    const float* bcls  = (const float*)d_in[find(18, 4)];
    const float* wbbox = (const float*)d_in[find(36 * 512, 5)];
    const float* bbbox = (const float*)d_in[find(36, 6)];
    const float* anch  = (const float*)d_in[find(NANCH * 4, 7)];

    char* ob = (char*)d_out;
    float* Btt               = (float*)(ob + OFF_BTT);
    unsigned long long* mask = (unsigned long long*)(ob + OFF_BTT);   // aliases dead Btt
    float* rpnT              = (float*)(ob + OFF_RPNT);
    float* sboxes            = (float*)(ob + OFF_SBOX);               // aliases dead rpnT
    int* keep                = (int*)(ob + OFF_KEEP);
    unsigned long long* keys = (unsigned long long*)(ob + OFF_KEYS);
    float* proposals         = (float*)(ob + OFF_PROP);
    unsigned int* rpart      = (unsigned int*)(ob + OFF_RPART);
    float* featT             = (float*)(ob + OFF_FEATT);
    float* outF              = (float*)d_out;

    hipLaunchKernelGGL(k_transpose_feat, dim3(75, 16), dim3(256), 0, stream, net, featT);
    hipLaunchKernelGGL(k_prep_w, dim3((CIN * KK + 255) / 256), dim3(256), 0, stream, wrpn, Btt);
    hipLaunchKernelGGL(k_conv3, dim3(38, 8), dim3(256), 0, stream, featT, Btt, brpn, rpnT);
    hipLaunchKernelGGL(k_heads, dim3(NPOS), dim3(256), 0, stream, rpnT, wcls, bcls, wbbox, bbbox, anch, proposals, keys);
    hipLaunchKernelGGL(k_rank_partial, dim3(85, NQ), dim3(256), 0, stream, keys, rpart);
    hipLaunchKernelGGL(k_zero_sboxes, dim3((PRE * 4 + 255) / 256), dim3(256), 0, stream, sboxes);
    hipLaunchKernelGGL(k_rank_scatter, dim3(85), dim3(256), 0, stream, rpart, proposals, sboxes);
    hipLaunchKernelGGL(k_nms_mask, dim3(NWORD, NWORD), dim3(64), 0, stream, sboxes, mask);
    hipLaunchKernelGGL(k_nms_scan, dim3(1), dim3(64), 0, stream, mask, keep);
    hipLaunchKernelGGL(k_gather_rois, dim3(1), dim3(256), 0, stream, sboxes, keep, outF);
    hipLaunchKernelGGL(k_crop, dim3(POST, 8), dim3(64), 0, stream, net, outF);
}

// Round 7
// 856.003 us; speedup vs baseline: 1.1472x; 1.1472x over previous
//
#include <hip/hip_runtime.h>
#include <stdint.h>

// Problem constants (fp32 everywhere)
#define NPOS 2394          // 38*63
#define CIN 512
#define KK 4608            // 512*9
#define NANCH 21546        // NPOS*9
#define PRE 6000
#define POST 300
#define NWORD 94           // ceil(6000/64)
#define NQ 8
#define QLEN 2694          // ceil(21546/8)

// ---- d_out scratch map (bytes). out bytes = 30,105,600. Peak use 25.35 MB.
// BTT   [0, 9437184)            Btt (s2->s3); mask 4,512,000 (s8->s9) aliases
// P0    [9437184, 14340096)     conv partial z=0 (s3->s4); sboxes+keep alias after
// P1    [14340096, 19243008)    conv partial z=1 (s3->s4)
// KEYS  [19243008, 19415376)    (s4->s5)
// PROP  [19415552, 19760288)    (s4->s7)
// RPART [19760384, 20449856)    (s5->s7)
// FEATT [20450048, 25352960)    (s1->s3)
#define OFF_BTT   0
#define OFF_P0    9437184
#define OFF_SBOX  9437184            // aliases dead P0
#define OFF_KEEP  9533440            // after sboxes (96,000 -> 9,533,184; pad)
#define OFF_P1    14340096
#define OFF_KEYS  19243008
#define OFF_PROP  19415552
#define OFF_RPART 19760384
#define OFF_FEATT 20450048

// fp32 (2394,512) channel-last transpose of net (512,2394), via LDS 32x32 tiles
__global__ __launch_bounds__(256) void k_transpose_feat(const float* __restrict__ in,
                                                        float* __restrict__ featT) {
    __shared__ float tl[32][33];
    int tx = threadIdx.x & 31, tg = threadIdx.x >> 5;     // 32 x 8
    int posBase = blockIdx.x * 32, ciBase = blockIdx.y * 32;
#pragma unroll
    for (int j = 0; j < 4; ++j) {
        int ci = ciBase + tg + j * 8;
        int pos = posBase + tx;
        tl[tg + j * 8][tx] = (pos < NPOS) ? in[(size_t)ci * NPOS + pos] : 0.f;
    }
    __syncthreads();
#pragma unroll
    for (int j = 0; j < 4; ++j) {
        int pos = posBase + tg + j * 8;
        int ci = ciBase + tx;
        if (pos < NPOS) featT[(size_t)pos * 512 + ci] = tl[tx][tg + j * 8];
    }
}

// w_rpn (co,ci,3,3) -> Btt[co][p*512+ci]
__global__ void k_prep_w(const float* __restrict__ w, float* __restrict__ Btt) {
    int idx = blockIdx.x * 256 + threadIdx.x;
    if (idx >= CIN * KK) return;
    int co = idx / KK;
    int rem = idx - co * KK;
    int p = rem >> 9;
    int ci = rem & 511;
    Btt[idx] = w[(co * CIN + ci) * 9 + p];
}

// 3x3 SAME conv as implicit-im2col fp32 SGEMM, split-K.
// Tile: 32 pos x 64 co, BK=32, grid (75, 8, 2); slice z does kc in [z*72, z*72+72).
// Writes raw partials to P[z] (no bias/ReLU here; fused into k_heads).
__global__ __launch_bounds__(256) void k_conv3(const float* __restrict__ featT,
                                               const float* __restrict__ Btt,
                                               float* __restrict__ P0,
                                               float* __restrict__ P1) {
    __shared__ float As[32][34];   // [k][pos]
    __shared__ float Bs[32][68];   // [k][co], float4-aligned rows
    int t = threadIdx.x;
    int posBase = blockIdx.x * 32, coBase = blockIdx.y * 32 * 2;  // 64-co tile
    int z = blockIdx.z;
    float* P = z ? P1 : P0;

    int tx = t & 15, ty = t >> 4;            // compute map: 4 co x 2 pos per thread
    float acc[2][4] = {{0.f}};

    int posr = t & 31, kqa = t >> 5;         // A staging: 32 pos x 8 k-quads
    int cor  = t & 63, wv  = t >> 6;         // B staging: 64 co x 4 waves (2 quads each)
    int pos = posBase + posr;
    int h = pos / 63, w = pos - h * 63;

    int kc0 = z * 72;
    for (int kc = kc0; kc < kc0 + 72; ++kc) {
        int p = kc >> 4;                     // tap (32 | 512, no straddle)
        int ci0 = (kc & 15) << 5;
        int kh = p / 3, kw = p - kh * 3;
        int hy = h + kh - 1, wx = w + kw - 1;
        float4 av = make_float4(0.f, 0.f, 0.f, 0.f);
        if ((unsigned)hy < 38u && (unsigned)wx < 63u && pos < NPOS)
            av = *reinterpret_cast<const float4*>(featT + ((hy * 63 + wx) * 512 + ci0 + kqa * 4));
        float4 bv0 = *reinterpret_cast<const float4*>(Btt + (size_t)(coBase + cor) * KK + kc * 32 + wv * 8);
        float4 bv1 = *reinterpret_cast<const float4*>(Btt + (size_t)(coBase + cor) * KK + kc * 32 + wv * 8 + 4);
        __syncthreads();
        As[kqa * 4 + 0][posr] = av.x; As[kqa * 4 + 1][posr] = av.y;
        As[kqa * 4 + 2][posr] = av.z; As[kqa * 4 + 3][posr] = av.w;
        Bs[wv * 8 + 0][cor] = bv0.x; Bs[wv * 8 + 1][cor] = bv0.y;
        Bs[wv * 8 + 2][cor] = bv0.z; Bs[wv * 8 + 3][cor] = bv0.w;
        Bs[wv * 8 + 4][cor] = bv1.x; Bs[wv * 8 + 5][cor] = bv1.y;
        Bs[wv * 8 + 6][cor] = bv1.z; Bs[wv * 8 + 7][cor] = bv1.w;
        __syncthreads();
#pragma unroll
        for (int k = 0; k < 32; ++k) {
            float2 a2 = *reinterpret_cast<const float2*>(&As[k][ty * 2]);
            float4 b4 = *reinterpret_cast<const float4*>(&Bs[k][tx * 4]);
            float a[2] = {a2.x, a2.y};
            float b[4] = {b4.x, b4.y, b4.z, b4.w};
#pragma unroll
            for (int i = 0; i < 2; ++i)
#pragma unroll
                for (int j = 0; j < 4; ++j) acc[i][j] += a[i] * b[j];
        }
    }
#pragma unroll
    for (int i = 0; i < 2; ++i) {
        int opos = posBase + ty * 2 + i;
        if (opos >= NPOS) continue;
#pragma unroll
        for (int j = 0; j < 4; ++j) {
            int co = coBase + tx * 4 + j;
            P[(size_t)opos * 512 + co] = acc[i][j];
        }
    }
}

// 1x1 heads (fuses conv bias+ReLU over P0+P1) + softmax-prob + decode + clip + key.
__global__ __launch_bounds__(256) void k_heads(const float* __restrict__ P0,
                                               const float* __restrict__ P1,
                                               const float* __restrict__ brpn,
                                               const float* __restrict__ wcls,
                                               const float* __restrict__ bcls,
                                               const float* __restrict__ wbbox,
                                               const float* __restrict__ bbbox,
                                               const float* __restrict__ anchors,
                                               float* __restrict__ proposals,
                                               unsigned long long* __restrict__ keys) {
    __shared__ float x[512];
    __shared__ float part[54][4];
    __shared__ float logit[54];
    int pos = blockIdx.x;
    int t = threadIdx.x;
    {
        float v0 = P0[(size_t)pos * 512 + t] + P1[(size_t)pos * 512 + t] + brpn[t];
        float v1 = P0[(size_t)pos * 512 + t + 256] + P1[(size_t)pos * 512 + t + 256] + brpn[t + 256];
        x[t] = v0 > 0.f ? v0 : 0.f;
        x[t + 256] = v1 > 0.f ? v1 : 0.f;
    }
    __syncthreads();
    if (t < 216) {
        int o = t >> 2, q = t & 3;
        const float* wr = (o < 18) ? (wcls + o * 512) : (wbbox + (o - 18) * 512);
        float s = 0.f;
        int base = q * 128;
#pragma unroll 4
        for (int k2 = 0; k2 < 128; ++k2) s += x[base + k2] * wr[base + k2];
        part[o][q] = s;
    }
    __syncthreads();
    if (t < 54) {
        float b = (t < 18) ? bcls[t] : bbbox[t - 18];
        logit[t] = part[t][0] + part[t][1] + part[t][2] + part[t][3] + b;
    }
    __syncthreads();
    if (t < 9) {
        int a = t;
        float bg = logit[a], fg = logit[9 + a];
        float score = 1.f / (1.f + expf(bg - fg));
        float dx = logit[18 + 4 * a], dy = logit[19 + 4 * a];
        float dw = logit[20 + 4 * a], dh = logit[21 + 4 * a];
        int idx = pos * 9 + a;
        float ax1 = anchors[idx * 4 + 0], ay1 = anchors[idx * 4 + 1];
        float ax2 = anchors[idx * 4 + 2], ay2 = anchors[idx * 4 + 3];
        float aw = ax2 - ax1 + 1.f, ah = ay2 - ay1 + 1.f;
        float cx = ax1 + 0.5f * aw, cy = ay1 + 0.5f * ah;
        float pcx = dx * aw + cx, pcy = dy * ah + cy;
        float pw = expf(dw) * aw, ph = expf(dh) * ah;
        float x1 = fminf(fmaxf(pcx - 0.5f * pw, 0.f), 999.f);
        float y1 = fminf(fmaxf(pcy - 0.5f * ph, 0.f), 599.f);
        float x2 = fminf(fmaxf(pcx + 0.5f * pw, 0.f), 999.f);
        float y2 = fminf(fmaxf(pcy + 0.5f * ph, 0.f), 599.f);
        proposals[idx * 4 + 0] = x1; proposals[idx * 4 + 1] = y1;
        proposals[idx * 4 + 2] = x2; proposals[idx * 4 + 3] = y2;
        union { float f; unsigned int i; } sv; sv.f = score;
        keys[idx] = (((unsigned long long)sv.i) << 32) |
                    (unsigned long long)(0xFFFFFFFFu - (unsigned)idx);
    }
}

// rank_i = #{j : key_j > key_i}; partial counts over 8 j-slices
__global__ __launch_bounds__(256) void k_rank_partial(const unsigned long long* __restrict__ keys,
                                                      unsigned int* __restrict__ rpart) {
    __shared__ unsigned long long kc[1024];
    int i = blockIdx.x * 256 + threadIdx.x;
    int q = blockIdx.y;
    unsigned long long myk = (i < NANCH) ? keys[i] : 0xFFFFFFFFFFFFFFFFull;
    int j0 = q * QLEN;
    int j1 = j0 + QLEN; if (j1 > NANCH) j1 = NANCH;
    unsigned int cnt = 0;
    for (int base = j0; base < j1; base += 1024) {
        int nload = j1 - base; if (nload > 1024) nload = 1024;
        __syncthreads();
        for (int u = threadIdx.x; u < 1024; u += 256)
            kc[u] = (base + u < j1) ? keys[base + u] : 0ull;
        __syncthreads();
        for (int u = 0; u < nload; ++u)
            cnt += (kc[u] > myk) ? 1u : 0u;
    }
    if (i < NANCH) rpart[i * NQ + q] = cnt;
}

__global__ void k_zero_sboxes(float* __restrict__ sboxes) {
    int i = blockIdx.x * 256 + threadIdx.x;
    if (i < PRE * 4) sboxes[i] = 0.f;
}

__global__ void k_rank_scatter(const unsigned int* __restrict__ rpart,
                               const float* __restrict__ proposals,
                               float* __restrict__ sboxes) {
    int i = blockIdx.x * 256 + threadIdx.x;
    if (i >= NANCH) return;
    unsigned int r = 0;
#pragma unroll
    for (int q = 0; q < NQ; q++) r += rpart[i * NQ + q];
    if (r < PRE) {
        sboxes[r * 4 + 0] = proposals[i * 4 + 0];
        sboxes[r * 4 + 1] = proposals[i * 4 + 1];
        sboxes[r * 4 + 2] = proposals[i * 4 + 2];
        sboxes[r * 4 + 3] = proposals[i * 4 + 3];
    }
}

// suppression bitmask
__global__ __launch_bounds__(64) void k_nms_mask(const float* __restrict__ sboxes,
                                                 unsigned long long* __restrict__ mask) {
    __shared__ float bx[64][4];
    int ib = blockIdx.x, jb = blockIdx.y;
    int lane = threadIdx.x;
    int j = jb * 64 + lane;
    if (j < PRE) {
        bx[lane][0] = sboxes[j * 4 + 0]; bx[lane][1] = sboxes[j * 4 + 1];
        bx[lane][2] = sboxes[j * 4 + 2]; bx[lane][3] = sboxes[j * 4 + 3];
    } else {
        bx[lane][0] = 3e8f; bx[lane][1] = 3e8f; bx[lane][2] = 3e8f; bx[lane][3] = 3e8f;
    }
    __syncthreads();
    int i = ib * 64 + lane;
    if (i >= PRE) return;
    float x1 = sboxes[i * 4 + 0], y1 = sboxes[i * 4 + 1];
    float x2 = sboxes[i * 4 + 2], y2 = sboxes[i * 4 + 3];
    float ar = (x2 - x1 + 1.f) * (y2 - y1 + 1.f);
    unsigned long long bits = 0;
#pragma unroll 4
    for (int u = 0; u < 64; u++) {
        int j2 = jb * 64 + u;
        float iw = fminf(x2, bx[u][2]) - fmaxf(x1, bx[u][0]) + 1.f;
        float ih = fminf(y2, bx[u][3]) - fmaxf(y1, bx[u][1]) + 1.f;
        iw = fmaxf(iw, 0.f); ih = fmaxf(ih, 0.f);
        float inter = iw * ih;
        float arj = (bx[u][2] - bx[u][0] + 1.f) * (bx[u][3] - bx[u][1] + 1.f);
        float iou = inter / (ar + arj - inter);
        if (iou > 0.7f && j2 > i) bits |= (1ull << u);
    }
    mask[(size_t)i * NWORD + jb] = bits;
}

// greedy scan v2: word-block iteration. Per 64-candidate block: one broadcast;
// per KEPT box: one 94-word row load (2 per-lane loads) + one refresh broadcast.
__global__ __launch_bounds__(64) void k_nms_scan(const unsigned long long* __restrict__ mask,
                                                 int* __restrict__ keep) {
    int lane = threadIdx.x;
    unsigned long long rem0 = 0, rem1 = 0;   // lane owns words lane, 64+lane
    int nk = 0;
    for (int b = 0; b < NWORD && nk < POST; ++b) {
        unsigned long long rm = (b < 64) ? __shfl(rem0, b) : __shfl(rem1, b - 64);
        unsigned long long valid = (b == NWORD - 1) ? ((1ull << 48) - 1) : ~0ull; // 6000-5952=48
        unsigned long long alive = ~rm & valid;
        while (alive) {
            int u = __ffsll((long long)alive) - 1;
            int i = b * 64 + u;
            if (lane == 0) keep[nk] = i;
            ++nk;
            if (nk == POST) break;
            const unsigned long long* row = mask + (size_t)i * NWORD;
            rem0 |= row[lane];
            if (lane < NWORD - 64) rem1 |= row[64 + lane];
            unsigned long long rmb = (b < 64) ? __shfl(rem0, b) : __shfl(rem1, b - 64);
            unsigned long long above = (u == 63) ? 0ull : (~0ull << (u + 1));
            alive = ~rmb & valid & above;
        }
    }
    for (int k2 = nk + lane; k2 < POST; k2 += 64) keep[k2] = PRE - 1;
}

// Single block: headers (roi box) written to the start of each of the roi's 8
// output chunks; reads complete before writes (barrier).
__global__ __launch_bounds__(256) void k_gather_rois(const float* sboxes, const int* keep,
                                                     float* outF) {
    int t = threadIdx.x;
    float4 box[2];
    int nr = 0;
    for (int r = t; r < POST; r += 256) {
        int ki = keep[r];
        if (ki < 0) ki = 0; if (ki > PRE - 1) ki = PRE - 1;
        box[nr++] = *reinterpret_cast<const float4*>(sboxes + ki * 4);
    }
    __syncthreads();
    nr = 0;
    for (int r = t; r < POST; r += 256) {
        float4 b = box[nr++];
#pragma unroll
        for (int cg = 0; cg < 8; ++cg)
            *reinterpret_cast<float4*>(outF + (size_t)(r * 512 + cg * 64) * 49) = b;
    }
}

// crop_and_resize(14) + 2x2 maxpool. One wave per (roi, 64-ch group).
__global__ __launch_bounds__(64) void k_crop(const float* __restrict__ net,
                                             float* out) {
    int r = blockIdx.x, cg = blockIdx.y;
    int lane = threadIdx.x;
    int c = cg * 64 + lane;
    const float4 b = *reinterpret_cast<const float4*>(out + (size_t)(r * 512 + cg * 64) * 49);
    float x1 = b.x, y1 = b.y, x2 = b.z, y2 = b.w;
    float by1 = (y1 / 16.f) / 37.f, bx1 = (x1 / 16.f) / 62.f;
    float by2 = (y2 / 16.f) / 37.f, bx2 = (x2 / 16.f) / 62.f;
    float dyn = by2 - by1, dxn = bx2 - bx1;
    const float* fc = net + (size_t)c * NPOS;
    float* orow = out + ((size_t)r * 512 + c) * 49;
#pragma unroll
    for (int oy = 0; oy < 7; ++oy) {
#pragma unroll
        for (int ox = 0; ox < 7; ++ox) {
            float vv[4];
#pragma unroll
            for (int dy = 0; dy < 2; ++dy) {
                int sy = 2 * oy + dy;
                float ty = (float)sy / 13.f;
                float ys = by1 * 37.f + (ty * dyn) * 37.f;
                float yf = floorf(ys);
                float wy = ys - yf;
                int y0  = (int)fminf(fmaxf(yf, 0.f), 37.f);
                int y1i = (int)fminf(fmaxf(yf + 1.f, 0.f), 37.f);
#pragma unroll
                for (int dxx = 0; dxx < 2; ++dxx) {
                    int sx = 2 * ox + dxx;
                    float tx = (float)sx / 13.f;
                    float xs = bx1 * 62.f + (tx * dxn) * 62.f;
                    float xf = floorf(xs);
                    float wx = xs - xf;
                    int x0  = (int)fminf(fmaxf(xf, 0.f), 62.f);
                    int x1i = (int)fminf(fmaxf(xf + 1.f, 0.f), 62.f);
                    float f00 = fc[y0 * 63 + x0];
                    float f01 = fc[y0 * 63 + x1i];
                    float f10 = fc[y1i * 63 + x0];
                    float f11 = fc[y1i * 63 + x1i];
                    vv[dy * 2 + dxx] = f00 * (1.f - wy) * (1.f - wx) + f01 * (1.f - wy) * wx +
                                       f10 * wy * (1.f - wx) + f11 * wy * wx;
                }
            }
            orow[oy * 7 + ox] = fmaxf(fmaxf(vv[0], vv[1]), fmaxf(vv[2], vv[3]));
        }
    }
}

extern "C" void kernel_launch(void* const* d_in, const int* in_sizes, int n_in,
                              void* d_out, int out_size, void* d_ws, size_t ws_size,
                              hipStream_t stream) {
    (void)d_ws; (void)ws_size;
    auto find = [&](int count, int fallback) {
        for (int i = 0; i < n_in; ++i) if (in_sizes[i] == count) return i;
        return fallback;
    };
    const float* net   = (const float*)d_in[find(NPOS * CIN, 0)];
    const float* wrpn  = (const float*)d_in[find(512 * KK, 1)];
    const float* brpn  = (const float*)d_in[find(512, 2)];
    const float* wcls  = (const float*)d_in[find(18 * 512, 3)];
    const float* bcls  = (const float*)d_in[find(18, 4)];
    const float* wbbox = (const float*)d_in[find(36 * 512, 5)];
    const float* bbbox = (const float*)d_in[find(36, 6)];
    const float* anch  = (const float*)d_in[find(NANCH * 4, 7)];

    char* ob = (char*)d_out;
    float* Btt               = (float*)(ob + OFF_BTT);
    unsigned long long* mask = (unsigned long long*)(ob + OFF_BTT);
    float* P0                = (float*)(ob + OFF_P0);
    float* P1                = (float*)(ob + OFF_P1);
    float* sboxes            = (float*)(ob + OFF_SBOX);
    int* keep                = (int*)(ob + OFF_KEEP);
    unsigned long long* keys = (unsigned long long*)(ob + OFF_KEYS);
    float* proposals         = (float*)(ob + OFF_PROP);
    unsigned int* rpart      = (unsigned int*)(ob + OFF_RPART);
    float* featT             = (float*)(ob + OFF_FEATT);
    float* outF              = (float*)d_out;

    hipLaunchKernelGGL(k_transpose_feat, dim3(75, 16), dim3(256), 0, stream, net, featT);
    hipLaunchKernelGGL(k_prep_w, dim3((CIN * KK + 255) / 256), dim3(256), 0, stream, wrpn, Btt);
    hipLaunchKernelGGL(k_conv3, dim3(75, 8, 2), dim3(256), 0, stream, featT, Btt, P0, P1);
    hipLaunchKernelGGL(k_heads, dim3(NPOS), dim3(256), 0, stream, P0, P1, brpn, wcls, bcls, wbbox, bbbox, anch, proposals, keys);
    hipLaunchKernelGGL(k_rank_partial, dim3(85, NQ), dim3(256), 0, stream, keys, rpart);
    hipLaunchKernelGGL(k_zero_sboxes, dim3((PRE * 4 + 255) / 256), dim3(256), 0, stream, sboxes);
    hipLaunchKernelGGL(k_rank_scatter, dim3(85), dim3(256), 0, stream, rpart, proposals, sboxes);
    hipLaunchKernelGGL(k_nms_mask, dim3(NWORD, NWORD), dim3(64), 0, stream, sboxes, mask);
    hipLaunchKernelGGL(k_nms_scan, dim3(1), dim3(64), 0, stream, mask, keep);
    hipLaunchKernelGGL(k_gather_rois, dim3(1), dim3(256), 0, stream, sboxes, keep, outF);
    hipLaunchKernelGGL(k_crop, dim3(POST, 8), dim3(64), 0, stream, net, outF);
}

// Round 8
// 617.479 us; speedup vs baseline: 1.5903x; 1.3863x over previous
//
#include <hip/hip_runtime.h>
#include <stdint.h>

// Problem constants (fp32 everywhere)
#define NPOS 2394          // 38*63
#define CIN 512
#define KK 4608            // 512*9
#define NANCH 21546        // NPOS*9
#define PRE 6000
#define POST 300
#define NWORD 94           // ceil(6000/64)
#define NQ 8
#define QLEN 2694          // ceil(21546/8)
#define FEATT_BYTES 4902912   // NPOS*512*4

// ---- d_out scratch map (bytes). out bytes = 30,105,600.
#define OFF_BTT   0
#define OFF_P0    9437184
#define OFF_SBOX  9437184            // aliases dead P0
#define OFF_KEEP  9533440
#define OFF_P1    14340096
#define OFF_KEYS  19243008
#define OFF_PROP  19415552
#define OFF_RPART 19760384
#define OFF_FEATT 20450048           // fallback location when ws too small

// fp32 (2394,512) channel-last transpose of net (512,2394), via LDS 32x32 tiles
__global__ __launch_bounds__(256) void k_transpose_feat(const float* __restrict__ in,
                                                        float* __restrict__ featT) {
    __shared__ float tl[32][33];
    int tx = threadIdx.x & 31, tg = threadIdx.x >> 5;     // 32 x 8
    int posBase = blockIdx.x * 32, ciBase = blockIdx.y * 32;
#pragma unroll
    for (int j = 0; j < 4; ++j) {
        int ci = ciBase + tg + j * 8;
        int pos = posBase + tx;
        tl[tg + j * 8][tx] = (pos < NPOS) ? in[(size_t)ci * NPOS + pos] : 0.f;
    }
    __syncthreads();
#pragma unroll
    for (int j = 0; j < 4; ++j) {
        int pos = posBase + tg + j * 8;
        int ci = ciBase + tx;
        if (pos < NPOS) featT[(size_t)pos * 512 + ci] = tl[tx][tg + j * 8];
    }
}

// w_rpn (co,ci,3,3) -> Btt[co][p*512+ci]
__global__ void k_prep_w(const float* __restrict__ w, float* __restrict__ Btt) {
    int idx = blockIdx.x * 256 + threadIdx.x;
    if (idx >= CIN * KK) return;
    int co = idx / KK;
    int rem = idx - co * KK;
    int p = rem >> 9;
    int ci = rem & 511;
    Btt[idx] = w[(co * CIN + ci) * 9 + p];
}

// 3x3 SAME conv as implicit-im2col fp32 SGEMM, split-K (32pos x 64co, BK=32, z in {0,1})
__global__ __launch_bounds__(256) void k_conv3(const float* __restrict__ featT,
                                               const float* __restrict__ Btt,
                                               float* __restrict__ P0,
                                               float* __restrict__ P1) {
    __shared__ float As[32][34];   // [k][pos]
    __shared__ float Bs[32][68];   // [k][co]
    int t = threadIdx.x;
    int posBase = blockIdx.x * 32, coBase = blockIdx.y * 32 * 2;
    int z = blockIdx.z;
    float* P = z ? P1 : P0;

    int tx = t & 15, ty = t >> 4;            // compute: 4 co x 2 pos per thread
    float acc[2][4] = {{0.f}};

    int posr = t & 31, kqa = t >> 5;         // A staging
    int cor  = t & 63, wv  = t >> 6;         // B staging
    int pos = posBase + posr;
    int h = pos / 63, w = pos - h * 63;

    int kc0 = z * 72;
    for (int kc = kc0; kc < kc0 + 72; ++kc) {
        int p = kc >> 4;
        int ci0 = (kc & 15) << 5;
        int kh = p / 3, kw = p - kh * 3;
        int hy = h + kh - 1, wx = w + kw - 1;
        float4 av = make_float4(0.f, 0.f, 0.f, 0.f);
        if ((unsigned)hy < 38u && (unsigned)wx < 63u && pos < NPOS)
            av = *reinterpret_cast<const float4*>(featT + ((hy * 63 + wx) * 512 + ci0 + kqa * 4));
        float4 bv0 = *reinterpret_cast<const float4*>(Btt + (size_t)(coBase + cor) * KK + kc * 32 + wv * 8);
        float4 bv1 = *reinterpret_cast<const float4*>(Btt + (size_t)(coBase + cor) * KK + kc * 32 + wv * 8 + 4);
        __syncthreads();
        As[kqa * 4 + 0][posr] = av.x; As[kqa * 4 + 1][posr] = av.y;
        As[kqa * 4 + 2][posr] = av.z; As[kqa * 4 + 3][posr] = av.w;
        Bs[wv * 8 + 0][cor] = bv0.x; Bs[wv * 8 + 1][cor] = bv0.y;
        Bs[wv * 8 + 2][cor] = bv0.z; Bs[wv * 8 + 3][cor] = bv0.w;
        Bs[wv * 8 + 4][cor] = bv1.x; Bs[wv * 8 + 5][cor] = bv1.y;
        Bs[wv * 8 + 6][cor] = bv1.z; Bs[wv * 8 + 7][cor] = bv1.w;
        __syncthreads();
#pragma unroll
        for (int k = 0; k < 32; ++k) {
            float2 a2 = *reinterpret_cast<const float2*>(&As[k][ty * 2]);
            float4 b4 = *reinterpret_cast<const float4*>(&Bs[k][tx * 4]);
            float a[2] = {a2.x, a2.y};
            float b[4] = {b4.x, b4.y, b4.z, b4.w};
#pragma unroll
            for (int i = 0; i < 2; ++i)
#pragma unroll
                for (int j = 0; j < 4; ++j) acc[i][j] += a[i] * b[j];
        }
    }
#pragma unroll
    for (int i = 0; i < 2; ++i) {
        int opos = posBase + ty * 2 + i;
        if (opos >= NPOS) continue;
#pragma unroll
        for (int j = 0; j < 4; ++j) {
            int co = coBase + tx * 4 + j;
            P[(size_t)opos * 512 + co] = acc[i][j];
        }
    }
}

// 1x1 heads (fuses conv bias+ReLU over P0+P1) + softmax-prob + decode + clip + key.
__global__ __launch_bounds__(256) void k_heads(const float* __restrict__ P0,
                                               const float* __restrict__ P1,
                                               const float* __restrict__ brpn,
                                               const float* __restrict__ wcls,
                                               const float* __restrict__ bcls,
                                               const float* __restrict__ wbbox,
                                               const float* __restrict__ bbbox,
                                               const float* __restrict__ anchors,
                                               float* __restrict__ proposals,
                                               unsigned long long* __restrict__ keys) {
    __shared__ float x[512];
    __shared__ float part[54][4];
    __shared__ float logit[54];
    int pos = blockIdx.x;
    int t = threadIdx.x;
    {
        float v0 = P0[(size_t)pos * 512 + t] + P1[(size_t)pos * 512 + t] + brpn[t];
        float v1 = P0[(size_t)pos * 512 + t + 256] + P1[(size_t)pos * 512 + t + 256] + brpn[t + 256];
        x[t] = v0 > 0.f ? v0 : 0.f;
        x[t + 256] = v1 > 0.f ? v1 : 0.f;
    }
    __syncthreads();
    if (t < 216) {
        int o = t >> 2, q = t & 3;
        const float* wr = (o < 18) ? (wcls + o * 512) : (wbbox + (o - 18) * 512);
        float s = 0.f;
        int base = q * 128;
#pragma unroll 4
        for (int k2 = 0; k2 < 128; ++k2) s += x[base + k2] * wr[base + k2];
        part[o][q] = s;
    }
    __syncthreads();
    if (t < 54) {
        float b = (t < 18) ? bcls[t] : bbbox[t - 18];
        logit[t] = part[t][0] + part[t][1] + part[t][2] + part[t][3] + b;
    }
    __syncthreads();
    if (t < 9) {
        int a = t;
        float bg = logit[a], fg = logit[9 + a];
        float score = 1.f / (1.f + expf(bg - fg));
        float dx = logit[18 + 4 * a], dy = logit[19 + 4 * a];
        float dw = logit[20 + 4 * a], dh = logit[21 + 4 * a];
        int idx = pos * 9 + a;
        float ax1 = anchors[idx * 4 + 0], ay1 = anchors[idx * 4 + 1];
        float ax2 = anchors[idx * 4 + 2], ay2 = anchors[idx * 4 + 3];
        float aw = ax2 - ax1 + 1.f, ah = ay2 - ay1 + 1.f;
        float cx = ax1 + 0.5f * aw, cy = ay1 + 0.5f * ah;
        float pcx = dx * aw + cx, pcy = dy * ah + cy;
        float pw = expf(dw) * aw, ph = expf(dh) * ah;
        float x1 = fminf(fmaxf(pcx - 0.5f * pw, 0.f), 999.f);
        float y1 = fminf(fmaxf(pcy - 0.5f * ph, 0.f), 599.f);
        float x2 = fminf(fmaxf(pcx + 0.5f * pw, 0.f), 999.f);
        float y2 = fminf(fmaxf(pcy + 0.5f * ph, 0.f), 599.f);
        proposals[idx * 4 + 0] = x1; proposals[idx * 4 + 1] = y1;
        proposals[idx * 4 + 2] = x2; proposals[idx * 4 + 3] = y2;
        union { float f; unsigned int i; } sv; sv.f = score;
        keys[idx] = (((unsigned long long)sv.i) << 32) |
                    (unsigned long long)(0xFFFFFFFFu - (unsigned)idx);
    }
}

__global__ __launch_bounds__(256) void k_rank_partial(const unsigned long long* __restrict__ keys,
                                                      unsigned int* __restrict__ rpart) {
    __shared__ unsigned long long kc[1024];
    int i = blockIdx.x * 256 + threadIdx.x;
    int q = blockIdx.y;
    unsigned long long myk = (i < NANCH) ? keys[i] : 0xFFFFFFFFFFFFFFFFull;
    int j0 = q * QLEN;
    int j1 = j0 + QLEN; if (j1 > NANCH) j1 = NANCH;
    unsigned int cnt = 0;
    for (int base = j0; base < j1; base += 1024) {
        int nload = j1 - base; if (nload > 1024) nload = 1024;
        __syncthreads();
        for (int u = threadIdx.x; u < 1024; u += 256)
            kc[u] = (base + u < j1) ? keys[base + u] : 0ull;
        __syncthreads();
        for (int u = 0; u < nload; ++u)
            cnt += (kc[u] > myk) ? 1u : 0u;
    }
    if (i < NANCH) rpart[i * NQ + q] = cnt;
}

__global__ void k_zero_sboxes(float* __restrict__ sboxes) {
    int i = blockIdx.x * 256 + threadIdx.x;
    if (i < PRE * 4) sboxes[i] = 0.f;
}

__global__ void k_rank_scatter(const unsigned int* __restrict__ rpart,
                               const float* __restrict__ proposals,
                               float* __restrict__ sboxes) {
    int i = blockIdx.x * 256 + threadIdx.x;
    if (i >= NANCH) return;
    unsigned int r = 0;
#pragma unroll
    for (int q = 0; q < NQ; q++) r += rpart[i * NQ + q];
    if (r < PRE) {
        sboxes[r * 4 + 0] = proposals[i * 4 + 0];
        sboxes[r * 4 + 1] = proposals[i * 4 + 1];
        sboxes[r * 4 + 2] = proposals[i * 4 + 2];
        sboxes[r * 4 + 3] = proposals[i * 4 + 3];
    }
}

__global__ __launch_bounds__(64) void k_nms_mask(const float* __restrict__ sboxes,
                                                 unsigned long long* __restrict__ mask) {
    __shared__ float bx[64][4];
    int ib = blockIdx.x, jb = blockIdx.y;
    int lane = threadIdx.x;
    int j = jb * 64 + lane;
    if (j < PRE) {
        bx[lane][0] = sboxes[j * 4 + 0]; bx[lane][1] = sboxes[j * 4 + 1];
        bx[lane][2] = sboxes[j * 4 + 2]; bx[lane][3] = sboxes[j * 4 + 3];
    } else {
        bx[lane][0] = 3e8f; bx[lane][1] = 3e8f; bx[lane][2] = 3e8f; bx[lane][3] = 3e8f;
    }
    __syncthreads();
    int i = ib * 64 + lane;
    if (i >= PRE) return;
    float x1 = sboxes[i * 4 + 0], y1 = sboxes[i * 4 + 1];
    float x2 = sboxes[i * 4 + 2], y2 = sboxes[i * 4 + 3];
    float ar = (x2 - x1 + 1.f) * (y2 - y1 + 1.f);
    unsigned long long bits = 0;
#pragma unroll 4
    for (int u = 0; u < 64; u++) {
        int j2 = jb * 64 + u;
        float iw = fminf(x2, bx[u][2]) - fmaxf(x1, bx[u][0]) + 1.f;
        float ih = fminf(y2, bx[u][3]) - fmaxf(y1, bx[u][1]) + 1.f;
        iw = fmaxf(iw, 0.f); ih = fmaxf(ih, 0.f);
        float inter = iw * ih;
        float arj = (bx[u][2] - bx[u][0] + 1.f) * (bx[u][3] - bx[u][1] + 1.f);
        float iou = inter / (ar + arj - inter);
        if (iou > 0.7f && j2 > i) bits |= (1ull << u);
    }
    mask[(size_t)i * NWORD + jb] = bits;
}

// greedy scan: word-block iteration (one broadcast per 64-block + one row-load per kept)
__global__ __launch_bounds__(64) void k_nms_scan(const unsigned long long* __restrict__ mask,
                                                 int* __restrict__ keep) {
    int lane = threadIdx.x;
    unsigned long long rem0 = 0, rem1 = 0;
    int nk = 0;
    for (int b = 0; b < NWORD && nk < POST; ++b) {
        unsigned long long rm = (b < 64) ? __shfl(rem0, b) : __shfl(rem1, b - 64);
        unsigned long long valid = (b == NWORD - 1) ? ((1ull << 48) - 1) : ~0ull;
        unsigned long long alive = ~rm & valid;
        while (alive) {
            int u = __ffsll((long long)alive) - 1;
            int i = b * 64 + u;
            if (lane == 0) keep[nk] = i;
            ++nk;
            if (nk == POST) break;
            const unsigned long long* row = mask + (size_t)i * NWORD;
            rem0 |= row[lane];
            if (lane < NWORD - 64) rem1 |= row[64 + lane];
            unsigned long long rmb = (b < 64) ? __shfl(rem0, b) : __shfl(rem1, b - 64);
            unsigned long long above = (u == 63) ? 0ull : (~0ull << (u + 1));
            alive = ~rmb & valid & above;
        }
    }
    for (int k2 = nk + lane; k2 < POST; k2 += 64) keep[k2] = PRE - 1;
}

// headers: roi box at the start of each of the roi's 8 output chunks
__global__ __launch_bounds__(256) void k_gather_rois(const float* sboxes, const int* keep,
                                                     float* outF) {
    int t = threadIdx.x;
    float4 box[2];
    int nr = 0;
    for (int r = t; r < POST; r += 256) {
        int ki = keep[r];
        if (ki < 0) ki = 0; if (ki > PRE - 1) ki = PRE - 1;
        box[nr++] = *reinterpret_cast<const float4*>(sboxes + ki * 4);
    }
    __syncthreads();
    nr = 0;
    for (int r = t; r < POST; r += 256) {
        float4 b = box[nr++];
#pragma unroll
        for (int cg = 0; cg < 8; ++cg)
            *reinterpret_cast<float4*>(outF + (size_t)(r * 512 + cg * 64) * 49) = b;
    }
}

// FAST crop: coalesced featT reads (lane=channel) + LDS-staged coalesced writes.
// grid (POST, 2), block 256 = 4 waves; wave w handles cg = blockIdx.y*4+w.
__global__ __launch_bounds__(256) void k_crop_fast(const float* __restrict__ featT,
                                                   float* out) {
    __shared__ float lds[4][49 * 65];   // [wave][e*65 + c_local], padded vs bank conflicts
    int r = blockIdx.x;
    int w = threadIdx.x >> 6, lane = threadIdx.x & 63;
    int cg = blockIdx.y * 4 + w;
    int c = cg * 64 + lane;
    float* chunk = out + (size_t)(r * 512 + cg * 64) * 49;
    const float4 b = *reinterpret_cast<const float4*>(chunk);   // wave-uniform broadcast
    float x1 = b.x, y1 = b.y, x2 = b.z, y2 = b.w;
    float by1 = (y1 / 16.f) / 37.f, bx1 = (x1 / 16.f) / 62.f;
    float by2 = (y2 / 16.f) / 37.f, bx2 = (x2 / 16.f) / 62.f;
    float dyn = by2 - by1, dxn = bx2 - bx1;
    for (int e = 0; e < 49; ++e) {
        int oy = e / 7, ox = e - oy * 7;
        float vv[4];
#pragma unroll
        for (int dy = 0; dy < 2; ++dy) {
            int sy = 2 * oy + dy;
            float ty = (float)sy / 13.f;
            float ys = by1 * 37.f + (ty * dyn) * 37.f;
            float yf = floorf(ys);
            float wy = ys - yf;
            int y0  = (int)fminf(fmaxf(yf, 0.f), 37.f);
            int y1i = (int)fminf(fmaxf(yf + 1.f, 0.f), 37.f);
#pragma unroll
            for (int dxx = 0; dxx < 2; ++dxx) {
                int sx = 2 * ox + dxx;
                float tx = (float)sx / 13.f;
                float xs = bx1 * 62.f + (tx * dxn) * 62.f;
                float xf = floorf(xs);
                float wx = xs - xf;
                int x0  = (int)fminf(fmaxf(xf, 0.f), 62.f);
                int x1i = (int)fminf(fmaxf(xf + 1.f, 0.f), 62.f);
                float f00 = featT[(size_t)(y0 * 63 + x0) * 512 + c];
                float f01 = featT[(size_t)(y0 * 63 + x1i) * 512 + c];
                float f10 = featT[(size_t)(y1i * 63 + x0) * 512 + c];
                float f11 = featT[(size_t)(y1i * 63 + x1i) * 512 + c];
                vv[dy * 2 + dxx] = f00 * (1.f - wy) * (1.f - wx) + f01 * (1.f - wy) * wx +
                                   f10 * wy * (1.f - wx) + f11 * wy * wx;
            }
        }
        lds[w][e * 65 + lane] = fmaxf(fmaxf(vv[0], vv[1]), fmaxf(vv[2], vv[3]));
    }
    __syncthreads();
    // linear coalesced write of the wave's 64x49 chunk
    for (int i = lane; i < 64 * 49; i += 64) {
        int cl = i / 49, e = i - cl * 49;
        chunk[i] = lds[w][e * 65 + cl];
    }
}

// SLOW fallback crop (R7 version, reads NCHW net) — used only if ws too small
__global__ __launch_bounds__(64) void k_crop_slow(const float* __restrict__ net,
                                                  float* out) {
    int r = blockIdx.x, cg = blockIdx.y;
    int lane = threadIdx.x;
    int c = cg * 64 + lane;
    const float4 b = *reinterpret_cast<const float4*>(out + (size_t)(r * 512 + cg * 64) * 49);
    float x1 = b.x, y1 = b.y, x2 = b.z, y2 = b.w;
    float by1 = (y1 / 16.f) / 37.f, bx1 = (x1 / 16.f) / 62.f;
    float by2 = (y2 / 16.f) / 37.f, bx2 = (x2 / 16.f) / 62.f;
    float dyn = by2 - by1, dxn = bx2 - bx1;
    const float* fc = net + (size_t)c * NPOS;
    float* orow = out + ((size_t)r * 512 + c) * 49;
    for (int e = 0; e < 49; ++e) {
        int oy = e / 7, ox = e - oy * 7;
        float vv[4];
#pragma unroll
        for (int dy = 0; dy < 2; ++dy) {
            int sy = 2 * oy + dy;
            float ty = (float)sy / 13.f;
            float ys = by1 * 37.f + (ty * dyn) * 37.f;
            float yf = floorf(ys);
            float wy = ys - yf;
            int y0  = (int)fminf(fmaxf(yf, 0.f), 37.f);
            int y1i = (int)fminf(fmaxf(yf + 1.f, 0.f), 37.f);
#pragma unroll
            for (int dxx = 0; dxx < 2; ++dxx) {
                int sx = 2 * ox + dxx;
                float tx = (float)sx / 13.f;
                float xs = bx1 * 62.f + (tx * dxn) * 62.f;
                float xf = floorf(xs);
                float wx = xs - xf;
                int x0  = (int)fminf(fmaxf(xf, 0.f), 62.f);
                int x1i = (int)fminf(fmaxf(xf + 1.f, 0.f), 62.f);
                float f00 = fc[y0 * 63 + x0];
                float f01 = fc[y0 * 63 + x1i];
                float f10 = fc[y1i * 63 + x0];
                float f11 = fc[y1i * 63 + x1i];
                vv[dy * 2 + dxx] = f00 * (1.f - wy) * (1.f - wx) + f01 * (1.f - wy) * wx +
                                   f10 * wy * (1.f - wx) + f11 * wy * wx;
            }
        }
        orow[e] = fmaxf(fmaxf(vv[0], vv[1]), fmaxf(vv[2], vv[3]));
    }
}

extern "C" void kernel_launch(void* const* d_in, const int* in_sizes, int n_in,
                              void* d_out, int out_size, void* d_ws, size_t ws_size,
                              hipStream_t stream) {
    auto find = [&](int count, int fallback) {
        for (int i = 0; i < n_in; ++i) if (in_sizes[i] == count) return i;
        return fallback;
    };
    const float* net   = (const float*)d_in[find(NPOS * CIN, 0)];
    const float* wrpn  = (const float*)d_in[find(512 * KK, 1)];
    const float* brpn  = (const float*)d_in[find(512, 2)];
    const float* wcls  = (const float*)d_in[find(18 * 512, 3)];
    const float* bcls  = (const float*)d_in[find(18, 4)];
    const float* wbbox = (const float*)d_in[find(36 * 512, 5)];
    const float* bbbox = (const float*)d_in[find(36, 6)];
    const float* anch  = (const float*)d_in[find(NANCH * 4, 7)];

    char* ob = (char*)d_out;
    float* Btt               = (float*)(ob + OFF_BTT);
    unsigned long long* mask = (unsigned long long*)(ob + OFF_BTT);
    float* P0                = (float*)(ob + OFF_P0);
    float* P1                = (float*)(ob + OFF_P1);
    float* sboxes            = (float*)(ob + OFF_SBOX);
    int* keep                = (int*)(ob + OFF_KEEP);
    unsigned long long* keys = (unsigned long long*)(ob + OFF_KEYS);
    float* proposals         = (float*)(ob + OFF_PROP);
    unsigned int* rpart      = (unsigned int*)(ob + OFF_RPART);
    float* outF              = (float*)d_out;

    // featT in d_ws if it fits (survives the output-overwriting crop -> fast path)
    const bool ws_ok = (ws_size >= (size_t)FEATT_BYTES);
    float* featT = ws_ok ? (float*)d_ws : (float*)(ob + OFF_FEATT);

    hipLaunchKernelGGL(k_transpose_feat, dim3(75, 16), dim3(256), 0, stream, net, featT);
    hipLaunchKernelGGL(k_prep_w, dim3((CIN * KK + 255) / 256), dim3(256), 0, stream, wrpn, Btt);
    hipLaunchKernelGGL(k_conv3, dim3(75, 8, 2), dim3(256), 0, stream, featT, Btt, P0, P1);
    hipLaunchKernelGGL(k_heads, dim3(NPOS), dim3(256), 0, stream, P0, P1, brpn, wcls, bcls, wbbox, bbbox, anch, proposals, keys);
    hipLaunchKernelGGL(k_rank_partial, dim3(85, NQ), dim3(256), 0, stream, keys, rpart);
    hipLaunchKernelGGL(k_zero_sboxes, dim3((PRE * 4 + 255) / 256), dim3(256), 0, stream, sboxes);
    hipLaunchKernelGGL(k_rank_scatter, dim3(85), dim3(256), 0, stream, rpart, proposals, sboxes);
    hipLaunchKernelGGL(k_nms_mask, dim3(NWORD, NWORD), dim3(64), 0, stream, sboxes, mask);
    hipLaunchKernelGGL(k_nms_scan, dim3(1), dim3(64), 0, stream, mask, keep);
    hipLaunchKernelGGL(k_gather_rois, dim3(1), dim3(256), 0, stream, sboxes, keep, outF);
    if (ws_ok)
        hipLaunchKernelGGL(k_crop_fast, dim3(POST, 2), dim3(256), 0, stream, featT, outF);
    else
        hipLaunchKernelGGL(k_crop_slow, dim3(POST, 8), dim3(64), 0, stream, net, outF);
}